// Round 5
// baseline (15540.160 us; speedup 1.0000x reference)
//
#include <hip/hip_runtime.h>
#include <hip/hip_bf16.h>
#include <stdint.h>

#define SQ   2048
#define NB   8
#define G4   1024
#define NROW 16384   // SQ*NB

typedef float f32x4 __attribute__((ext_vector_type(4)));
typedef short bf16x8 __attribute__((ext_vector_type(8)));
typedef uint32_t u32;
typedef unsigned long long u64;

// ---------------- helpers ----------------
__device__ __forceinline__ f32x4 mfma16(bf16x8 a, bf16x8 b, f32x4 c) {
  return __builtin_amdgcn_mfma_f32_16x16x32_bf16(a, b, c, 0, 0, 0);
}
__device__ __forceinline__ u32 pk_bf16(float lo, float hi) {
  u32 r;
  asm("v_cvt_pk_bf16_f32 %0, %1, %2" : "=v"(r) : "v"(lo), "v"(hi));
  return r;
}
__device__ __forceinline__ float bf_lo(u32 u){ union{u32 a; float f;} x; x.a = u << 16;        return x.f; }
__device__ __forceinline__ float bf_hi(u32 u){ union{u32 a; float f;} x; x.a = u & 0xffff0000u; return x.f; }

__device__ __forceinline__ float sigm(float x)   { return 1.0f / (1.0f + __expf(-x)); }
__device__ __forceinline__ float tanh_f(float x) { return 1.0f - 2.0f / (__expf(2.0f * x) + 1.0f); }

// =====================================================================
// Kernel 1: x_proj = x @ Wih^T + bih  -> bf16, layout [dir][m=t*8+b][1024]
// (identical to the R2 version that passed)
// =====================================================================
__global__ __launch_bounds__(256) void xproj_gemm(
    const float* __restrict__ x,
    const float* __restrict__ WihF, const float* __restrict__ bihF,
    const float* __restrict__ WihB, const float* __restrict__ bihB,
    uint16_t* __restrict__ xp)
{
  const int dir = blockIdx.z;
  const float* Wih = dir ? WihB : WihF;
  const float* bih = dir ? bihB : bihF;
  char* xpd = (char*)xp + (size_t)dir * ((size_t)NROW * G4 * 2);

  const int g0 = blockIdx.y * 128;
  const int m0 = blockIdx.x * 128;

  __shared__ union {
    struct { short A[128 * 72]; short B[128 * 72]; } s;  // 144B row pitch
    short T[128 * 136];                                  // transpose stage
  } u;
  __shared__ float biasS[128];

  const int tid  = threadIdx.x;
  const int lane = tid & 63;
  const int w    = tid >> 6;
  const int wg   = w >> 1;
  const int wm   = w & 1;
  const int l15  = lane & 15;
  const int l4   = lane >> 4;

  if (tid < 128) biasS[tid] = bih[g0 + tid];

  f32x4 acc[4][4] = {};

  const int r_st = tid >> 1;
  const int half = tid & 1;
  const int mrow_st = m0 + r_st;
  const int xb = mrow_st & 7;
  const int xt = mrow_st >> 3;
  const float* xrow = x + ((size_t)xb * SQ + xt) * 256;
  const float* wrow = Wih + (size_t)(g0 + r_st) * 256;

  for (int s = 0; s < 4; ++s) {
    const int k0 = s * 64;
    __syncthreads();
    {
      const float* srcA = wrow + k0 + half * 32;
      const float* srcB = xrow + k0 + half * 32;
      short* dstA = u.s.A + r_st * 72 + half * 32;
      short* dstB = u.s.B + r_st * 72 + half * 32;
      #pragma unroll
      for (int j = 0; j < 4; ++j) {
        f32x4 a0 = *(const f32x4*)(srcA + j * 8);
        f32x4 a1 = *(const f32x4*)(srcA + j * 8 + 4);
        uint4 pa = { pk_bf16(a0.x, a0.y), pk_bf16(a0.z, a0.w),
                     pk_bf16(a1.x, a1.y), pk_bf16(a1.z, a1.w) };
        *(uint4*)(dstA + j * 8) = pa;
        f32x4 b0 = *(const f32x4*)(srcB + j * 8);
        f32x4 b1 = *(const f32x4*)(srcB + j * 8 + 4);
        uint4 pb = { pk_bf16(b0.x, b0.y), pk_bf16(b0.z, b0.w),
                     pk_bf16(b1.x, b1.y), pk_bf16(b1.z, b1.w) };
        *(uint4*)(dstB + j * 8) = pb;
      }
    }
    __syncthreads();
    #pragma unroll
    for (int kt = 0; kt < 2; ++kt) {
      bf16x8 aF[4], bF[4];
      #pragma unroll
      for (int i = 0; i < 4; ++i) {
        const int ar = wg * 64 + i * 16 + l15;
        const int br = wm * 64 + i * 16 + l15;
        aF[i] = *(const bf16x8*)(u.s.A + ar * 72 + kt * 32 + l4 * 8);
        bF[i] = *(const bf16x8*)(u.s.B + br * 72 + kt * 32 + l4 * 8);
      }
      #pragma unroll
      for (int i = 0; i < 4; ++i)
        #pragma unroll
        for (int j = 0; j < 4; ++j)
          acc[i][j] = mfma16(aF[i], bF[j], acc[i][j]);
    }
  }

  __syncthreads();
  #pragma unroll
  for (int i = 0; i < 4; ++i) {
    const f32x4 bv = *(const f32x4*)(biasS + wg * 64 + i * 16 + l4 * 4);
    #pragma unroll
    for (int j = 0; j < 4; ++j) {
      f32x4 v = acc[i][j];
      v.x += bv.x; v.y += bv.y; v.z += bv.z; v.w += bv.w;
      const int mrow = wm * 64 + j * 16 + l15;
      const int gcol = wg * 64 + i * 16 + l4 * 4;
      uint2 p; p.x = pk_bf16(v.x, v.y); p.y = pk_bf16(v.z, v.w);
      *(uint2*)(u.T + mrow * 136 + gcol) = p;
    }
  }
  __syncthreads();
  {
    const char* trow = (const char*)(u.T + r_st * 136);
    char* orow = xpd + (size_t)(m0 + r_st) * 2048 + g0 * 2;
    #pragma unroll
    for (int j = 0; j < 8; ++j) {
      const int local = half * 128 + j * 16;
      uint4 v = *(const uint4*)(trow + local);
      *(uint4*)(orow + local) = v;
    }
  }
}

// =====================================================================
// Kernel 2: BiLSTM scan, 4 WGs per direction (8 active CUs). Each WG
// owns 64 h-dims x all 4 gates -> 4 M-tiles/wave -> weight fragments in
// 128 ARCH VGPRs (pure builtin MFMA, compiler-managed hazards; no LDS,
// no barriers). ALL h flows through a global u64 exchange: each word
// packs {2 bf16 h | 32-bit step tag} stored/loaded with relaxed agent
// atomics — tag and data travel atomically together, so no fences.
// Exchange is memset(0) every launch (no stale-tag hazard).
// Layout: exch[dir][slot=t&1][batch 8][128 u64 words], word i of a
// batch row holds h-dims {2i, 2i+1}.
// =====================================================================
__global__ __launch_bounds__(256, 1) void lstm_rec(
    const float* __restrict__ WhhF, const float* __restrict__ WhhB,
    const uint16_t* __restrict__ xp, float* __restrict__ out, u64* exch)
{
  const int bid = blockIdx.x;
  const int dir = bid & 7;          // XCD heuristic: dir's 4 WGs share one XCD
  const int c   = bid >> 3;         // h-dim chunk 0..3
  if (dir > 1) return;

  const float* Whh = dir ? WhhB : WhhF;
  const uint16_t* xpd = xp + (size_t)dir * NROW * G4;
  u64* ex = exch + (size_t)dir * 2048;

  const int tid  = threadIdx.x;
  const int lane = tid & 63;
  const int w    = tid >> 6;
  const int l15  = lane & 15;
  const int l4   = lane >> 4;
  const int bcl  = lane & 7;          // batch this lane serves
  const int qsel = (lane >> 3) & 1;   // duplicate-column half: picks acc elems

  // ---- persistent weight fragments: gate g, k-block kt (128 VGPRs)
  bf16x8 W[4][8];
  #pragma unroll
  for (int g = 0; g < 4; ++g) {
    const int row = g * 256 + c * 64 + w * 16 + l15;
    const float* src = Whh + (size_t)row * 256 + l4 * 8;
    #pragma unroll
    for (int kt = 0; kt < 8; ++kt) {
      f32x4 v0 = *(const f32x4*)(src + kt * 32);
      f32x4 v1 = *(const f32x4*)(src + kt * 32 + 4);
      union { bf16x8 v; u32 u[4]; } pk;
      pk.u[0] = pk_bf16(v0.x, v0.y); pk.u[1] = pk_bf16(v0.z, v0.w);
      pk.u[2] = pk_bf16(v1.x, v1.y); pk.u[3] = pk_bf16(v1.z, v1.w);
      W[g][kt] = pk.v;
    }
  }

  // the 2 h-dims this lane owns in the epilogue
  const int dme = c * 64 + w * 16 + l4 * 4 + qsel * 2;
  float c0 = 0.0f, c1 = 0.0f;

  // prologue xp (2 bf16 per gate)
  u32 xq[4];
  {
    const int tt0 = dir ? SQ - 1 : 0;
    const uint16_t* xr = xpd + (size_t)(tt0 * 8 + bcl) * 1024 + dme;
    #pragma unroll
    for (int g = 0; g < 4; ++g) xq[g] = *(const u32*)(xr + g * 256);
  }

  u64* wr = ex + (size_t)bcl * 128 + (dme >> 1);   // + slot*1024
  u64* rd = ex + (size_t)bcl * 128 + l4 * 4;       // + slot*1024 + kt*16 + j

  #pragma unroll 1
  for (int t = 0; t < SQ; ++t) {
    const int tt = dir ? (SQ - 1 - t) : t;
    f32x4 acc[4] = {};

    if (t > 0) {
      u64 pq[8][4];
      u64* rb = rd + (size_t)((t - 1) & 1) * 1024;
      const u32 want = (u32)t;

      #pragma unroll
      for (int kt = 0; kt < 8; ++kt)
        #pragma unroll
        for (int j = 0; j < 4; ++j)
          pq[kt][j] = __hip_atomic_load(rb + kt * 16 + j, __ATOMIC_RELAXED,
                                        __HIP_MEMORY_SCOPE_AGENT);
      while (true) {
        bool ok = true;
        #pragma unroll
        for (int kt = 0; kt < 8; ++kt)
          #pragma unroll
          for (int j = 0; j < 4; ++j)
            ok = ok && ((u32)pq[kt][j] == want);
        if (__all(ok)) break;
        __builtin_amdgcn_s_sleep(1);
        #pragma unroll
        for (int kt = 0; kt < 8; ++kt)
          #pragma unroll
          for (int j = 0; j < 4; ++j)
            pq[kt][j] = __hip_atomic_load(rb + kt * 16 + j, __ATOMIC_RELAXED,
                                          __HIP_MEMORY_SCOPE_AGENT);
      }

      // gates += Whh * h : 32 MFMAs, 4 independent accumulator chains
      #pragma unroll
      for (int kt = 0; kt < 8; ++kt) {
        union { bf16x8 v; u32 u[4]; } bb;
        #pragma unroll
        for (int j = 0; j < 4; ++j) bb.u[j] = (u32)(pq[kt][j] >> 32);
        #pragma unroll
        for (int g = 0; g < 4; ++g)
          acc[g] = mfma16(W[g][kt], bb.v, acc[g]);
      }
    }

    // ---- epilogue: qsel picks elems {0,1} or {2,3} (dup MFMA columns)
    float P0[4], P1[4];
    #pragma unroll
    for (int g = 0; g < 4; ++g) {
      const float a0 = qsel ? acc[g].z : acc[g].x;
      const float a1 = qsel ? acc[g].w : acc[g].y;
      P0[g] = a0 + bf_lo(xq[g]);
      P1[g] = a1 + bf_hi(xq[g]);
    }
    const float i0 = sigm(P0[0]), f0 = sigm(P0[1]), g0v = tanh_f(P0[2]), o0 = sigm(P0[3]);
    const float i1 = sigm(P1[0]), f1 = sigm(P1[1]), g1v = tanh_f(P1[2]), o1 = sigm(P1[3]);
    c0 = f0 * c0 + i0 * g0v;
    c1 = f1 * c1 + i1 * g1v;
    const float h0 = o0 * tanh_f(c0);
    const float h1 = o1 * tanh_f(c1);

    // ---- stores: out (f32x2) + exchange word {h pair | tag t+1}
    *(float2*)(out + ((size_t)bcl * SQ + tt) * 512 + dir * 256 + dme) =
        make_float2(h0, h1);
    __hip_atomic_store(wr + (size_t)(t & 1) * 1024,
                       ((u64)pk_bf16(h0, h1) << 32) | (u64)(u32)(t + 1),
                       __ATOMIC_RELAXED, __HIP_MEMORY_SCOPE_AGENT);

    // ---- prefetch next xp
    {
      const int tn = (t + 1 < SQ) ? t + 1 : SQ - 1;
      const int ttn = dir ? (SQ - 1 - tn) : tn;
      const uint16_t* xr = xpd + (size_t)(ttn * 8 + bcl) * 1024 + dme;
      #pragma unroll
      for (int g = 0; g < 4; ++g) xq[g] = *(const u32*)(xr + g * 256);
    }
  }
}

// =====================================================================
extern "C" void kernel_launch(void* const* d_in, const int* in_sizes, int n_in,
                              void* d_out, int out_size, void* d_ws, size_t ws_size,
                              hipStream_t stream) {
  const float* x    = (const float*)d_in[0];
  const float* WihF = (const float*)d_in[1];
  const float* bihF = (const float*)d_in[2];
  const float* WhhF = (const float*)d_in[3];
  const float* WihB = (const float*)d_in[4];
  const float* bihB = (const float*)d_in[5];
  const float* WhhB = (const float*)d_in[6];
  float* out = (float*)d_out;

  const size_t XPB = (size_t)2 * NROW * G4 * 2;     // 64 MiB bf16 x-projection
  const size_t EXB = (size_t)4096 * sizeof(u64);    // 32 KiB exchange
  if (ws_size < XPB + EXB) return;
  uint16_t* xpw = (uint16_t*)d_ws;
  u64* exch = (u64*)((char*)d_ws + XPB);

  hipMemsetAsync(exch, 0, EXB, stream);             // zero tags every call
  xproj_gemm<<<dim3(128, 8, 2), dim3(256), 0, stream>>>(x, WihF, bihF, WihB, bihB, xpw);
  lstm_rec<<<dim3(32), dim3(256), 0, stream>>>(WhhF, WhhB, xpw, out, exch);
}

// Round 6
// 5971.532 us; speedup vs baseline: 2.6024x; 2.6024x over previous
//
#include <hip/hip_runtime.h>
#include <hip/hip_bf16.h>
#include <stdint.h>

#define SQ   2048
#define NB   8
#define G4   1024
#define NROW 16384   // SQ*NB

typedef float f32x4 __attribute__((ext_vector_type(4)));
typedef short bf16x8 __attribute__((ext_vector_type(8)));
typedef uint32_t u32;
typedef unsigned long long u64;

// ---------------- helpers ----------------
__device__ __forceinline__ f32x4 mfma16(bf16x8 a, bf16x8 b, f32x4 c) {
  return __builtin_amdgcn_mfma_f32_16x16x32_bf16(a, b, c, 0, 0, 0);
}
__device__ __forceinline__ u32 pk_bf16(float lo, float hi) {
  u32 r;
  asm("v_cvt_pk_bf16_f32 %0, %1, %2" : "=v"(r) : "v"(lo), "v"(hi));
  return r;
}
__device__ __forceinline__ float bf_lo(u32 u){ union{u32 a; float f;} x; x.a = u << 16;        return x.f; }
__device__ __forceinline__ float bf_hi(u32 u){ union{u32 a; float f;} x; x.a = u & 0xffff0000u; return x.f; }

__device__ __forceinline__ float sigm(float x)   { return 1.0f / (1.0f + __expf(-x)); }
__device__ __forceinline__ float tanh_f(float x) { return 1.0f - 2.0f / (__expf(2.0f * x) + 1.0f); }

// =====================================================================
// Kernel 1: x_proj = x @ Wih^T + bih  -> bf16, layout [dir][m=t*8+b][1024]
// (unchanged from the version that passed in R2/R5)
// =====================================================================
__global__ __launch_bounds__(256) void xproj_gemm(
    const float* __restrict__ x,
    const float* __restrict__ WihF, const float* __restrict__ bihF,
    const float* __restrict__ WihB, const float* __restrict__ bihB,
    uint16_t* __restrict__ xp)
{
  const int dir = blockIdx.z;
  const float* Wih = dir ? WihB : WihF;
  const float* bih = dir ? bihB : bihF;
  char* xpd = (char*)xp + (size_t)dir * ((size_t)NROW * G4 * 2);

  const int g0 = blockIdx.y * 128;
  const int m0 = blockIdx.x * 128;

  __shared__ union {
    struct { short A[128 * 72]; short B[128 * 72]; } s;  // 144B row pitch
    short T[128 * 136];                                  // transpose stage
  } u;
  __shared__ float biasS[128];

  const int tid  = threadIdx.x;
  const int lane = tid & 63;
  const int w    = tid >> 6;
  const int wg   = w >> 1;
  const int wm   = w & 1;
  const int l15  = lane & 15;
  const int l4   = lane >> 4;

  if (tid < 128) biasS[tid] = bih[g0 + tid];

  f32x4 acc[4][4] = {};

  const int r_st = tid >> 1;
  const int half = tid & 1;
  const int mrow_st = m0 + r_st;
  const int xb = mrow_st & 7;
  const int xt = mrow_st >> 3;
  const float* xrow = x + ((size_t)xb * SQ + xt) * 256;
  const float* wrow = Wih + (size_t)(g0 + r_st) * 256;

  for (int s = 0; s < 4; ++s) {
    const int k0 = s * 64;
    __syncthreads();
    {
      const float* srcA = wrow + k0 + half * 32;
      const float* srcB = xrow + k0 + half * 32;
      short* dstA = u.s.A + r_st * 72 + half * 32;
      short* dstB = u.s.B + r_st * 72 + half * 32;
      #pragma unroll
      for (int j = 0; j < 4; ++j) {
        f32x4 a0 = *(const f32x4*)(srcA + j * 8);
        f32x4 a1 = *(const f32x4*)(srcA + j * 8 + 4);
        uint4 pa = { pk_bf16(a0.x, a0.y), pk_bf16(a0.z, a0.w),
                     pk_bf16(a1.x, a1.y), pk_bf16(a1.z, a1.w) };
        *(uint4*)(dstA + j * 8) = pa;
        f32x4 b0 = *(const f32x4*)(srcB + j * 8);
        f32x4 b1 = *(const f32x4*)(srcB + j * 8 + 4);
        uint4 pb = { pk_bf16(b0.x, b0.y), pk_bf16(b0.z, b0.w),
                     pk_bf16(b1.x, b1.y), pk_bf16(b1.z, b1.w) };
        *(uint4*)(dstB + j * 8) = pb;
      }
    }
    __syncthreads();
    #pragma unroll
    for (int kt = 0; kt < 2; ++kt) {
      bf16x8 aF[4], bF[4];
      #pragma unroll
      for (int i = 0; i < 4; ++i) {
        const int ar = wg * 64 + i * 16 + l15;
        const int br = wm * 64 + i * 16 + l15;
        aF[i] = *(const bf16x8*)(u.s.A + ar * 72 + kt * 32 + l4 * 8);
        bF[i] = *(const bf16x8*)(u.s.B + br * 72 + kt * 32 + l4 * 8);
      }
      #pragma unroll
      for (int i = 0; i < 4; ++i)
        #pragma unroll
        for (int j = 0; j < 4; ++j)
          acc[i][j] = mfma16(aF[i], bF[j], acc[i][j]);
    }
  }

  __syncthreads();
  #pragma unroll
  for (int i = 0; i < 4; ++i) {
    const f32x4 bv = *(const f32x4*)(biasS + wg * 64 + i * 16 + l4 * 4);
    #pragma unroll
    for (int j = 0; j < 4; ++j) {
      f32x4 v = acc[i][j];
      v.x += bv.x; v.y += bv.y; v.z += bv.z; v.w += bv.w;
      const int mrow = wm * 64 + j * 16 + l15;
      const int gcol = wg * 64 + i * 16 + l4 * 4;
      uint2 p; p.x = pk_bf16(v.x, v.y); p.y = pk_bf16(v.z, v.w);
      *(uint2*)(u.T + mrow * 136 + gcol) = p;
    }
  }
  __syncthreads();
  {
    const char* trow = (const char*)(u.T + r_st * 136);
    char* orow = xpd + (size_t)(m0 + r_st) * 2048 + g0 * 2;
    #pragma unroll
    for (int j = 0; j < 8; ++j) {
      const int local = half * 128 + j * 16;
      uint4 v = *(const uint4*)(trow + local);
      *(uint4*)(orow + local) = v;
    }
  }
}

// =====================================================================
// Kernel 2: BiLSTM scan. 2 WGs/dir x 8 waves (512 thr, 2 waves/SIMD).
// Wave w owns ALL 4 gates x 16 h-dims (dims HALF*128 + w*16..+16):
// weights = 4 tiles x 8 kt = 128 VGPRs/lane, pure builtin MFMA, epilogue
// wave-local. Exchange: each lane publishes ONE u64 {2bf16 h | tag t+1}
// (relaxed agent atomic) and polls ONE partner word (preloaded during
// the previous step's epilogue so MALL latency overlaps); staged word
// goes to LDS hP and is shared by all 8 waves. One raw s_barrier +
// lgkmcnt(0) per step; no vmcnt drain.
// =====================================================================
template<int HALF>
__device__ __forceinline__ void lstm_body(
    const float* __restrict__ Whh, const uint16_t* __restrict__ xpd,
    float* __restrict__ out, u64* ex_me, u64* ex_pt, int dir,
    uint16_t (*hT)[8][136], uint16_t (*hP)[8][136])
{
  const int tid  = threadIdx.x;
  const int lane = tid & 63;
  const int w    = tid >> 6;          // wave 0..7
  const int l15  = lane & 15;
  const int l4   = lane >> 4;
  const int bcl  = lane & 7;          // batch this lane serves
  const int qsel = (lane >> 3) & 1;   // duplicate-column half select

  // ---- persistent weights: gate g, k-block kt; rows g*256 + HALF*128 + w*16
  bf16x8 W[4][8];
  #pragma unroll
  for (int g = 0; g < 4; ++g) {
    const int row = g * 256 + HALF * 128 + w * 16 + l15;
    const float* src = Whh + (size_t)row * 256 + l4 * 8;
    #pragma unroll
    for (int kt = 0; kt < 8; ++kt) {
      f32x4 v0 = *(const f32x4*)(src + kt * 32);
      f32x4 v1 = *(const f32x4*)(src + kt * 32 + 4);
      union { bf16x8 v; u32 u[4]; } pk;
      pk.u[0] = pk_bf16(v0.x, v0.y); pk.u[1] = pk_bf16(v0.z, v0.w);
      pk.u[2] = pk_bf16(v1.x, v1.y); pk.u[3] = pk_bf16(v1.z, v1.w);
      W[g][kt] = pk.v;
    }
  }

  const int d0   = w * 16 + l4 * 4 + qsel * 2;     // local dim pair this lane owns
  const int word = bcl * 64 + (d0 >> 1);           // publish word index (bijective)
  float c0 = 0.0f, c1 = 0.0f;

  // prologue: xp for step 0 (2 bf16 per gate)
  u32 xq[4];
  {
    const int tt0 = dir ? SQ - 1 : 0;
    const uint16_t* xr = xpd + (size_t)(tt0 * 8 + bcl) * 1024 + HALF * 128 + d0;
    #pragma unroll
    for (int g = 0; g < 4; ++g) xq[g] = *(const u32*)(xr + g * 256);
  }

  u64 pw = 0;   // preloaded partner word for the NEXT step

  #pragma unroll 1
  for (int t = 0; t < SQ; ++t) {
    const int tt = dir ? (SQ - 1 - t) : t;

    // ---- stage partner word into LDS (poll own single word)
    if (t > 0) {
      const u32 want = (u32)t;
      u64* pa = ex_pt + (size_t)((t - 1) & 1) * 512 + tid;
      while ((u32)pw != want) {
        __builtin_amdgcn_s_sleep(1);
        pw = __hip_atomic_load(pa, __ATOMIC_RELAXED, __HIP_MEMORY_SCOPE_AGENT);
      }
      // word tid -> (batch w, dim pair lane)
      *(u32*)&hP[(t - 1) & 1][w][lane * 2] = (u32)(pw >> 32);
    }
    asm volatile("s_waitcnt lgkmcnt(0)" ::: "memory");
    __builtin_amdgcn_s_barrier();

    // ---- gates = Whh * h (32 MFMAs; B-frags from LDS, both halves)
    f32x4 acc[4] = {};
    if (t > 0) {
      #pragma unroll
      for (int ko = 0; ko < 4; ++ko) {
        const bf16x8 bO = *(const bf16x8*)&hT[t & 1][bcl][ko * 32 + l4 * 8];
        #pragma unroll
        for (int g = 0; g < 4; ++g) acc[g] = mfma16(W[g][HALF * 4 + ko], bO, acc[g]);
        const bf16x8 bP = *(const bf16x8*)&hP[(t - 1) & 1][bcl][ko * 32 + l4 * 8];
        #pragma unroll
        for (int g = 0; g < 4; ++g) acc[g] = mfma16(W[g][(1 - HALF) * 4 + ko], bP, acc[g]);
      }
    }

    // ---- epilogue (wave-local: all 4 gates present)
    float P0[4], P1[4];
    #pragma unroll
    for (int g = 0; g < 4; ++g) {
      P0[g] = (qsel ? acc[g].z : acc[g].x) + bf_lo(xq[g]);
      P1[g] = (qsel ? acc[g].w : acc[g].y) + bf_hi(xq[g]);
    }
    const float i0 = sigm(P0[0]), f0 = sigm(P0[1]), g0v = tanh_f(P0[2]), o0 = sigm(P0[3]);
    const float i1 = sigm(P1[0]), f1 = sigm(P1[1]), g1v = tanh_f(P1[2]), o1 = sigm(P1[3]);
    c0 = f0 * c0 + i0 * g0v;
    c1 = f1 * c1 + i1 * g1v;
    const float h0 = o0 * tanh_f(c0);
    const float h1 = o1 * tanh_f(c1);

    // ---- stores: out (f32x2), publish (one u64 atomic), own hT (LDS)
    *(float2*)(out + ((size_t)bcl * SQ + tt) * 512 + dir * 256 + HALF * 128 + d0) =
        make_float2(h0, h1);
    const u32 h01 = pk_bf16(h0, h1);
    __hip_atomic_store(ex_me + (size_t)(t & 1) * 512 + word,
                       ((u64)h01 << 32) | (u64)(u32)(t + 1),
                       __ATOMIC_RELAXED, __HIP_MEMORY_SCOPE_AGENT);
    *(u32*)&hT[(t + 1) & 1][bcl][d0] = h01;

    // ---- prefetch next xp + preload next partner word (latency overlap)
    {
      const int tn = (t + 1 < SQ) ? t + 1 : SQ - 1;
      const int ttn = dir ? (SQ - 1 - tn) : tn;
      const uint16_t* xr = xpd + (size_t)(ttn * 8 + bcl) * 1024 + HALF * 128 + d0;
      #pragma unroll
      for (int g = 0; g < 4; ++g) xq[g] = *(const u32*)(xr + g * 256);
    }
    pw = __hip_atomic_load(ex_pt + (size_t)(t & 1) * 512 + tid,
                           __ATOMIC_RELAXED, __HIP_MEMORY_SCOPE_AGENT);
  }
}

__global__ __launch_bounds__(512, 2) void lstm_rec(
    const float* __restrict__ WhhF, const float* __restrict__ WhhB,
    const uint16_t* __restrict__ xp, float* __restrict__ out, u64* exch)
{
  __shared__ uint16_t hT[2][8][136];   // own half h, double-buffered (272B pitch)
  __shared__ uint16_t hP[2][8][136];   // partner half h, double-buffered

  const int bid  = blockIdx.x;
  const int dir  = bid & 7;            // XCD heuristic: pair shares an XCD
  const int half = bid >> 3;
  if (dir > 1) return;                 // 12 idle blocks exit

  const float* Whh = dir ? WhhB : WhhF;
  const uint16_t* xpd = xp + (size_t)dir * NROW * G4;
  u64* eme = exch + (size_t)(dir * 2 + half) * 1024;        // 2 slots x 512 words
  u64* ept = exch + (size_t)(dir * 2 + (1 - half)) * 1024;

  if (half == 0) lstm_body<0>(Whh, xpd, out, eme, ept, dir, hT, hP);
  else           lstm_body<1>(Whh, xpd, out, eme, ept, dir, hT, hP);
}

// =====================================================================
extern "C" void kernel_launch(void* const* d_in, const int* in_sizes, int n_in,
                              void* d_out, int out_size, void* d_ws, size_t ws_size,
                              hipStream_t stream) {
  const float* x    = (const float*)d_in[0];
  const float* WihF = (const float*)d_in[1];
  const float* bihF = (const float*)d_in[2];
  const float* WhhF = (const float*)d_in[3];
  const float* WihB = (const float*)d_in[4];
  const float* bihB = (const float*)d_in[5];
  const float* WhhB = (const float*)d_in[6];
  float* out = (float*)d_out;

  const size_t XPB = (size_t)2 * NROW * G4 * 2;     // 64 MiB bf16 x-projection
  const size_t EXB = (size_t)4096 * sizeof(u64);    // 32 KiB exchange
  if (ws_size < XPB + EXB) return;
  uint16_t* xpw = (uint16_t*)d_ws;
  u64* exch = (u64*)((char*)d_ws + XPB);

  hipMemsetAsync(exch, 0, EXB, stream);             // fresh tags every call
  xproj_gemm<<<dim3(128, 8, 2), dim3(256), 0, stream>>>(x, WihF, bihF, WihB, bihB, xpw);
  lstm_rec<<<dim3(16), dim3(512), 0, stream>>>(WhhF, WhhB, xpw, out, exch);
}